// Round 1
// baseline (1836.603 us; speedup 1.0000x reference)
//
#include <hip/hip_runtime.h>
#include <math.h>

// TreeLSTM on a complete binary tree, N = 2^15-1.
// Tree is implicit: children(i) = 2i+1, 2i+2; internal 0..16382, leaves 16383..32766.
// Per level d (14..0): gates = x[lvl] @ W_ih^T + mean_h @ W_hh^T + b_ih + b_hh,
// LSTM cell, write h,c. Then pooled mean + W_fc dot.
//
// fp32 baseline. Tile: 32 nodes x (64 ch x 4 gate groups); thread = (ch, node-group),
// owns all 4 gates of one channel for 8 nodes -> cell epilogue is thread-local.

#define N_NODES 32767
#define IN_C    512
#define H_C     256
#define NH      (N_NODES * H_C)   // 8388352 floats
#define BM      32

template <bool LEAF>
__global__ __launch_bounds__(256)
void level_kernel(const float* __restrict__ x,
                  const float* __restrict__ W_ih,
                  const float* __restrict__ W_hh,
                  const float* __restrict__ b_ih,
                  const float* __restrict__ b_hh,
                  float* __restrict__ h,
                  float* __restrict__ c,
                  int lo, int n)
{
    // As: [16 kk][32 nodes] pad to 36 (2-way max bank aliasing on write, b128-aligned reads)
    // Bs: [16 kk][64 ch * 4 q] pad 256->260
    __shared__ __align__(16) float As[16 * 36];
    __shared__ __align__(16) float Bs[16 * 260];

    const int t   = threadIdx.x;
    const int ch  = t & 63;        // channel within 64-wide channel block
    const int ng  = t >> 6;        // node group 0..3 (8 nodes each)
    const int chb = blockIdx.y;    // channel block 0..3
    const int m0  = blockIdx.x * BM;

    float acc[8][4];
#pragma unroll
    for (int j = 0; j < 8; ++j)
#pragma unroll
        for (int q = 0; q < 4; ++q) acc[j][q] = 0.f;

    const int KT   = LEAF ? IN_C : (IN_C + H_C);
    const int kk_s = t & 15;
    const int r0   = t >> 4;       // 0..15

    for (int k0 = 0; k0 < KT; k0 += 16) {
        // ---- stage A: 32 nodes x 16 k  (2 elems/thread) ----
#pragma unroll
        for (int e = 0; e < 2; ++e) {
            const int m  = r0 + e * 16;     // 0..31
            const int mi = m0 + m;
            float v = 0.f;
            if (mi < n) {
                const int node = lo + mi;
                const int k = k0 + kk_s;
                if (k < IN_C) {
                    v = x[node * IN_C + k];
                } else {
                    const int k2 = k - IN_C;
                    v = 0.5f * (h[(2 * node + 1) * H_C + k2] +
                                h[(2 * node + 2) * H_C + k2]);
                }
            }
            As[kk_s * 36 + m] = v;
        }
        // ---- stage B: 256 gate rows x 16 k (16 elems/thread) ----
#pragma unroll
        for (int e = 0; e < 16; ++e) {
            const int rl   = r0 + e * 16;   // 0..255
            const int chs  = rl & 63;
            const int qs   = rl >> 6;
            const int grow = qs * H_C + chb * 64 + chs;   // gate row 0..1023
            const int k    = k0 + kk_s;
            const float v  = (k < IN_C) ? W_ih[grow * IN_C + k]
                                        : W_hh[grow * H_C + (k - IN_C)];
            Bs[kk_s * 260 + chs * 4 + qs] = v;
        }
        __syncthreads();
        // ---- MACs ----
#pragma unroll
        for (int kk = 0; kk < 16; ++kk) {
            const float4 a0 = *(const float4*)(&As[kk * 36 + ng * 8]);
            const float4 a1 = *(const float4*)(&As[kk * 36 + ng * 8 + 4]);
            const float4 bb = *(const float4*)(&Bs[kk * 260 + ch * 4]);
            const float av[8] = {a0.x, a0.y, a0.z, a0.w, a1.x, a1.y, a1.z, a1.w};
            const float bv[4] = {bb.x, bb.y, bb.z, bb.w};
#pragma unroll
            for (int j = 0; j < 8; ++j)
#pragma unroll
                for (int q = 0; q < 4; ++q)
                    acc[j][q] = fmaf(av[j], bv[q], acc[j][q]);
        }
        __syncthreads();
    }

    // ---- epilogue: LSTM cell, thread-local (owns i,f,g,o of channel CH) ----
    const int CH = chb * 64 + ch;
    float bsum[4];
#pragma unroll
    for (int q = 0; q < 4; ++q)
        bsum[q] = b_ih[q * H_C + CH] + b_hh[q * H_C + CH];

#pragma unroll
    for (int j = 0; j < 8; ++j) {
        const int mi = m0 + ng * 8 + j;
        if (mi < n) {
            const int node = lo + mi;
            const float gi_raw = acc[j][0] + bsum[0];
            const float gf_raw = acc[j][1] + bsum[1];
            const float gg_raw = acc[j][2] + bsum[2];
            const float go_raw = acc[j][3] + bsum[3];
            const float gi = 1.f / (1.f + expf(-gi_raw));
            const float gf = 1.f / (1.f + expf(-gf_raw));
            const float gg = tanhf(gg_raw);
            const float go = 1.f / (1.f + expf(-go_raw));
            float mc = 0.f;
            if (!LEAF)
                mc = 0.5f * (c[(2 * node + 1) * H_C + CH] +
                             c[(2 * node + 2) * H_C + CH]);
            const float cn = gf * mc + gi * gg;
            const float hn = go * tanhf(cn);
            c[node * H_C + CH] = cn;
            h[node * H_C + CH] = hn;
        }
    }
}

// pooled mean + fc, two stages
__global__ __launch_bounds__(256)
void reduce_rows(const float* __restrict__ h, float* __restrict__ part)
{
    const int t = threadIdx.x;
    const int b = blockIdx.x;
    float s = 0.f;
    for (int r = 0; r < 128; ++r) {
        const int row = b * 128 + r;
        if (row < N_NODES) s += h[row * H_C + t];
    }
    part[b * H_C + t] = s;
}

__global__ __launch_bounds__(256)
void reduce_final(const float* __restrict__ part,
                  const float* __restrict__ W_fc,
                  const float* __restrict__ b_fc,
                  float* __restrict__ out)
{
    __shared__ float sm[256];
    const int t = threadIdx.x;
    float s = 0.f;
    for (int j = 0; j < 256; ++j) s += part[j * H_C + t];
    s = s * (1.0f / (float)N_NODES) * W_fc[t];
    sm[t] = s;
    __syncthreads();
    for (int st = 128; st > 0; st >>= 1) {
        if (t < st) sm[t] += sm[t + st];
        __syncthreads();
    }
    if (t == 0) out[0] = sm[0] + b_fc[0];
}

extern "C" void kernel_launch(void* const* d_in, const int* in_sizes, int n_in,
                              void* d_out, int out_size, void* d_ws, size_t ws_size,
                              hipStream_t stream)
{
    const float* x    = (const float*)d_in[0];
    // d_in[1] = edge_index (int32) — tree is implicit, unused
    const float* W_ih = (const float*)d_in[2];
    const float* W_hh = (const float*)d_in[3];
    const float* b_ih = (const float*)d_in[4];
    const float* b_hh = (const float*)d_in[5];
    const float* W_fc = (const float*)d_in[6];
    const float* b_fc = (const float*)d_in[7];
    float* out = (float*)d_out;

    float* h    = (float*)d_ws;
    float* c    = h + NH;
    float* part = c + NH;   // 256*256 floats

    // leaves (level 14): K = 512, mean_h = mean_c = 0
    {
        const int n  = 1 << 14;
        const int lo = n - 1;
        dim3 grid((n + BM - 1) / BM, 4);
        level_kernel<true><<<grid, 256, 0, stream>>>(x, W_ih, W_hh, b_ih, b_hh,
                                                     h, c, lo, n);
    }
    // internal levels 13..0
    for (int d = 13; d >= 0; --d) {
        const int n  = 1 << d;
        const int lo = n - 1;
        dim3 grid((n + BM - 1) / BM, 4);
        level_kernel<false><<<grid, 256, 0, stream>>>(x, W_ih, W_hh, b_ih, b_hh,
                                                      h, c, lo, n);
    }
    reduce_rows<<<256, 256, 0, stream>>>(h, part);
    reduce_final<<<1, 256, 0, stream>>>(part, W_fc, b_fc, out);
}

// Round 2
// 544.723 us; speedup vs baseline: 3.3716x; 3.3716x over previous
//
#include <hip/hip_runtime.h>
#include <math.h>

// TreeLSTM, complete binary tree N = 2^15-1 (implicit: children(i)=2i+1,2i+2).
// Round 2: bf16 MFMA GEMM (16x16x32), m97 recipe: 128x128 tile, BK=32,
// global_load_lds width-16 staging. Gate-permuted B layout so all 4 gates of a
// (node,channel) land in one lane -> thread-local LSTM cell epilogue.
// x,W pre-converted to bf16; h stored bf16; c stays fp32.

#define N_NODES 32767
#define IN_C    512
#define H_C     256

typedef __bf16 bf16x8 __attribute__((ext_vector_type(8)));
typedef float  f32x4  __attribute__((ext_vector_type(4)));

__device__ __forceinline__ void gload_lds16(const void* g, void* l) {
    __builtin_amdgcn_global_load_lds(
        (const __attribute__((address_space(1))) unsigned int*)g,
        (__attribute__((address_space(3))) unsigned int*)l,
        16, 0, 0);
}

// ---- fp32 -> bf16 converters ----
__global__ __launch_bounds__(256)
void conv_bf16_kernel(const float* __restrict__ src, __bf16* __restrict__ dst, int n8)
{
    const int i = blockIdx.x * 256 + threadIdx.x;
    if (i < n8) {
        const float4* s4 = (const float4*)src;
        const float4 a = s4[2 * i];
        const float4 b = s4[2 * i + 1];
        bf16x8 o;
        o[0] = (__bf16)a.x; o[1] = (__bf16)a.y; o[2] = (__bf16)a.z; o[3] = (__bf16)a.w;
        o[4] = (__bf16)b.x; o[5] = (__bf16)b.y; o[6] = (__bf16)b.z; o[7] = (__bf16)b.w;
        *(bf16x8*)(dst + 8 * i) = o;
    }
}

// ---- per-level fused GEMM + LSTM cell ----
// grid = (8 channel-slabs, ceil(n/128)); block = 256 (4 waves, 2x2 of 64x64).
// B column permutation within a block: n_local -> gate q=(n_local>>4)&3,
// channel cc = (n_local&15) + (n_local>>6)*16. Lane (l15) at wave wn then holds
// channel CH = cb*32 + wn*16 + l15 and its 4 gates across the ni fragment index.
template <bool LEAF>
__global__ __launch_bounds__(256)
void level_mfma(const __bf16* __restrict__ xb,
                const __bf16* __restrict__ wih,
                const __bf16* __restrict__ whh,
                const float* __restrict__ b_ih,
                const float* __restrict__ b_hh,
                __bf16* __restrict__ hb,
                float* __restrict__ c,
                int lo, int n)
{
    __shared__ __bf16 As[128 * 32];   // [m][k], unpadded (global_load_lds layout)
    __shared__ __bf16 Bs[128 * 32];   // [n_local][k]

    const int t    = threadIdx.x;
    const int lane = t & 63;
    const int wv   = t >> 6;
    const int wm   = wv >> 1;
    const int wn   = wv & 1;
    const int quad = lane >> 4;
    const int l15  = lane & 15;
    const int cb   = blockIdx.x;          // channel slab 0..7 (32 channels)
    const int m0   = blockIdx.y * 128;

    f32x4 acc[4][4];
#pragma unroll
    for (int mi = 0; mi < 4; ++mi)
#pragma unroll
        for (int ni = 0; ni < 4; ++ni) acc[mi][ni] = (f32x4)0.f;

    const int KT = LEAF ? IN_C : (IN_C + H_C);

    for (int k0 = 0; k0 < KT; k0 += 32) {
        // ---- stage B: 128 rows x 32 k via global_load_lds (per-lane global addr,
        //      wave-uniform LDS base). chunk = 16 rows = 1 KiB. ----
#pragma unroll
        for (int e = 0; e < 2; ++e) {
            const int chunk = wv * 2 + e;
            const int nl    = chunk * 16 + (lane >> 2);
            const int q     = (nl >> 4) & 3;
            const int cc    = (nl & 15) + ((nl >> 6) << 4);
            const int grow  = q * H_C + cb * 32 + cc;
            const void* g;
            if (LEAF || k0 < IN_C)
                g = (const char*)(wih + grow * IN_C + k0) + (lane & 3) * 16;
            else
                g = (const char*)(whh + grow * H_C + (k0 - IN_C)) + (lane & 3) * 16;
            gload_lds16(g, (char*)Bs + chunk * 1024);
        }
        // ---- stage A ----
        if (LEAF || k0 < IN_C) {
            // from pre-converted x (bf16). OOB rows (m>=n) read mapped garbage
            // (node < N_NODES always here) and are never stored.
#pragma unroll
            for (int e = 0; e < 2; ++e) {
                const int chunk = wv * 2 + e;
                const int row   = chunk * 16 + (lane >> 2);
                const int node  = lo + m0 + row;
                const void* g = (const char*)(xb + node * IN_C + k0) + (lane & 3) * 16;
                gload_lds16(g, (char*)As + chunk * 1024);
            }
        } else {
            // mean of children h (bf16), VGPR-staged: thread = 16 elems.
            const int row  = t >> 1;
            const int kh   = (t & 1) * 16;
            const int node = lo + m0 + row;
            const int k2   = k0 + kh - IN_C;
            const bf16x8* hl = (const bf16x8*)(hb + (2 * node + 1) * H_C + k2);
            const bf16x8* hr = (const bf16x8*)(hb + (2 * node + 2) * H_C + k2);
            const bf16x8 a0 = hl[0], a1 = hl[1], b0 = hr[0], b1 = hr[1];
            bf16x8 o0, o1;
#pragma unroll
            for (int j = 0; j < 8; ++j) {
                o0[j] = (__bf16)(0.5f * ((float)a0[j] + (float)b0[j]));
                o1[j] = (__bf16)(0.5f * ((float)a1[j] + (float)b1[j]));
            }
            bf16x8* dst = (bf16x8*)(As + row * 32 + kh);
            dst[0] = o0;
            dst[1] = o1;
        }
        __syncthreads();
        // ---- fragments + MFMA ----
        bf16x8 af[4], bfr[4];
#pragma unroll
        for (int mi = 0; mi < 4; ++mi)
            af[mi] = *(const bf16x8*)(As + (wm * 64 + mi * 16 + l15) * 32 + quad * 8);
#pragma unroll
        for (int ni = 0; ni < 4; ++ni)
            bfr[ni] = *(const bf16x8*)(Bs + (wn * 64 + ni * 16 + l15) * 32 + quad * 8);
#pragma unroll
        for (int mi = 0; mi < 4; ++mi)
#pragma unroll
            for (int ni = 0; ni < 4; ++ni)
                acc[mi][ni] = __builtin_amdgcn_mfma_f32_16x16x32_bf16(
                    af[mi], bfr[ni], acc[mi][ni], 0, 0, 0);
        __syncthreads();
    }

    // ---- epilogue: thread-local LSTM cell (lane owns all 4 gates of CH) ----
    const int CH = cb * 32 + wn * 16 + l15;
    float bs[4];
#pragma unroll
    for (int q = 0; q < 4; ++q) bs[q] = b_ih[q * H_C + CH] + b_hh[q * H_C + CH];

#pragma unroll
    for (int mi = 0; mi < 4; ++mi) {
#pragma unroll
        for (int r = 0; r < 4; ++r) {
            const int mrow = wm * 64 + mi * 16 + quad * 4 + r;
            const int m = m0 + mrow;
            if (m < n) {
                const int node = lo + m;
                const float gi_raw = acc[mi][0][r] + bs[0];
                const float gf_raw = acc[mi][1][r] + bs[1];
                const float gg_raw = acc[mi][2][r] + bs[2];
                const float go_raw = acc[mi][3][r] + bs[3];
                const float gi = 1.f / (1.f + expf(-gi_raw));
                const float gf = 1.f / (1.f + expf(-gf_raw));
                const float gg = tanhf(gg_raw);
                const float go = 1.f / (1.f + expf(-go_raw));
                float mc = 0.f;
                if (!LEAF)
                    mc = 0.5f * (c[(2 * node + 1) * H_C + CH] +
                                 c[(2 * node + 2) * H_C + CH]);
                const float cn = gf * mc + gi * gg;
                const float hn = go * tanhf(cn);
                c[node * H_C + CH] = cn;
                hb[node * H_C + CH] = (__bf16)hn;
            }
        }
    }
}

// ---- pooled mean + fc ----
__global__ __launch_bounds__(256)
void reduce_rows(const __bf16* __restrict__ hb, float* __restrict__ part)
{
    const int tcol = threadIdx.x;
    const int b = blockIdx.x;
    float s = 0.f;
    for (int r = 0; r < 128; ++r) {
        const int row = b * 128 + r;
        if (row < N_NODES) s += (float)hb[row * H_C + tcol];
    }
    part[b * H_C + tcol] = s;
}

__global__ __launch_bounds__(256)
void reduce_final(const float* __restrict__ part,
                  const float* __restrict__ W_fc,
                  const float* __restrict__ b_fc,
                  float* __restrict__ out)
{
    __shared__ float sm[256];
    const int t = threadIdx.x;
    float s = 0.f;
    for (int j = 0; j < 256; ++j) s += part[j * H_C + t];
    s = s * (1.0f / (float)N_NODES) * W_fc[t];
    sm[t] = s;
    __syncthreads();
    for (int st = 128; st > 0; st >>= 1) {
        if (t < st) sm[t] += sm[t + st];
        __syncthreads();
    }
    if (t == 0) out[0] = sm[0] + b_fc[0];
}

extern "C" void kernel_launch(void* const* d_in, const int* in_sizes, int n_in,
                              void* d_out, int out_size, void* d_ws, size_t ws_size,
                              hipStream_t stream)
{
    const float* x    = (const float*)d_in[0];
    // d_in[1] = edge_index — tree is implicit, unused
    const float* W_ih = (const float*)d_in[2];
    const float* W_hh = (const float*)d_in[3];
    const float* b_ih = (const float*)d_in[4];
    const float* b_hh = (const float*)d_in[5];
    const float* W_fc = (const float*)d_in[6];
    const float* b_fc = (const float*)d_in[7];
    float* out = (float*)d_out;

    // workspace layout (all 16B aligned)
    char* w = (char*)d_ws;
    __bf16* xb   = (__bf16*)w;                 w += (size_t)N_NODES * IN_C * 2;  // 33.6 MB
    __bf16* hb   = (__bf16*)w;                 w += (size_t)N_NODES * H_C * 2;   // 16.8 MB
    float*  c    = (float*)w;                  w += (size_t)N_NODES * H_C * 4;   // 33.6 MB
    __bf16* wihb = (__bf16*)w;                 w += (size_t)4 * H_C * IN_C * 2;  // 1.0 MB
    __bf16* whhb = (__bf16*)w;                 w += (size_t)4 * H_C * H_C * 2;   // 0.5 MB
    float*  part = (float*)w;                                                    // 256 KB

    // convert x and W to bf16 (every call — same work each launch)
    {
        const int n8x = (N_NODES * IN_C) / 8;               // 2,097,088
        conv_bf16_kernel<<<(n8x + 255) / 256, 256, 0, stream>>>(x, xb, n8x);
        const int n8i = (4 * H_C * IN_C) / 8;               // 65,536
        conv_bf16_kernel<<<(n8i + 255) / 256, 256, 0, stream>>>(W_ih, wihb, n8i);
        const int n8h = (4 * H_C * H_C) / 8;                // 32,768
        conv_bf16_kernel<<<(n8h + 255) / 256, 256, 0, stream>>>(W_hh, whhb, n8h);
    }

    // leaves (level 14): K=512
    {
        const int n  = 1 << 14;
        const int lo = n - 1;
        dim3 grid(8, n / 128);
        level_mfma<true><<<grid, 256, 0, stream>>>(xb, wihb, whhb, b_ih, b_hh,
                                                   hb, c, lo, n);
    }
    // internal levels 13..0: K=768
    for (int d = 13; d >= 0; --d) {
        const int n  = 1 << d;
        const int lo = n - 1;
        dim3 grid(8, (n + 127) / 128);
        level_mfma<false><<<grid, 256, 0, stream>>>(xb, wihb, whhb, b_ih, b_hh,
                                                    hb, c, lo, n);
    }
    reduce_rows<<<256, 256, 0, stream>>>(hb, part);
    reduce_final<<<1, 256, 0, stream>>>(part, W_fc, b_fc, out);
}

// Round 3
// 449.218 us; speedup vs baseline: 4.0884x; 1.2126x over previous
//
#include <hip/hip_runtime.h>
#include <math.h>

// TreeLSTM, complete binary tree N = 2^15-1 (implicit: children(i)=2i+1,2i+2).
// Round 3: split the recurrence. One bulk MFMA GEMM computes x@W_ih^T for ALL
// nodes (leaves get the full LSTM cell fused; internal nodes store gates_x bf16).
// Each level kernel then only does mean_h@W_hh^T (K=256, 8 k-iters) + gates_x
// add + cell -> 3x less serial latency-bound work. Fast exp/rcp transcendentals.

#define N_NODES 32767
#define N_LEAF0 16383     // first leaf node index
#define IN_C    512
#define H_C     256

typedef __bf16 bf16x8 __attribute__((ext_vector_type(8)));
typedef float  f32x4  __attribute__((ext_vector_type(4)));

__device__ __forceinline__ void gload_lds16(const void* g, void* l) {
    __builtin_amdgcn_global_load_lds(
        (const __attribute__((address_space(1))) unsigned int*)g,
        (__attribute__((address_space(3))) unsigned int*)l,
        16, 0, 0);
}

__device__ __forceinline__ float fast_rcp(float x) { return __builtin_amdgcn_rcpf(x); }
__device__ __forceinline__ float sigm(float x)     { return fast_rcp(1.f + __expf(-x)); }
__device__ __forceinline__ float tanh_fast(float x){ return 2.f * fast_rcp(1.f + __expf(-2.f * x)) - 1.f; }

// ---- fp32 -> bf16 converter (weights only) ----
__global__ __launch_bounds__(256)
void conv_bf16_kernel(const float* __restrict__ src, __bf16* __restrict__ dst, int n8)
{
    const int i = blockIdx.x * 256 + threadIdx.x;
    if (i < n8) {
        const float4* s4 = (const float4*)src;
        const float4 a = s4[2 * i];
        const float4 b = s4[2 * i + 1];
        bf16x8 o;
        o[0] = (__bf16)a.x; o[1] = (__bf16)a.y; o[2] = (__bf16)a.z; o[3] = (__bf16)a.w;
        o[4] = (__bf16)b.x; o[5] = (__bf16)b.y; o[6] = (__bf16)b.z; o[7] = (__bf16)b.w;
        *(bf16x8*)(dst + 8 * i) = o;
    }
}

// ---- bulk kernel: acc = x @ W_ih^T for ALL 32767 nodes.
// Leaf rows (node >= 16383): full LSTM cell (mean_h = mean_c = 0) -> h,c.
// Internal rows: store raw gates to gates_x (bf16, [node][gate q][256 ch]).
// grid = (8 channel-slabs, 256 m-tiles of 128); block = 256 = 2x2 waves of 64x64.
// B column permutation per 128-slab: q = ni, channel = cb*32 + wn*16 + l15,
// so a lane owns all 4 gates of one (node, channel).
__global__ __launch_bounds__(256)
void bulk_xw(const float* __restrict__ x,
             const __bf16* __restrict__ wih,
             const float* __restrict__ b_ih,
             const float* __restrict__ b_hh,
             __bf16* __restrict__ hb,
             float* __restrict__ c,
             __bf16* __restrict__ gx)
{
    __shared__ __bf16 As[128 * 32];
    __shared__ __bf16 Bs[128 * 32];

    const int t    = threadIdx.x;
    const int lane = t & 63;
    const int wv   = t >> 6;
    const int wm   = wv >> 1;
    const int wn   = wv & 1;
    const int quad = lane >> 4;
    const int l15  = lane & 15;
    const int cb   = blockIdx.x;
    const int m0   = blockIdx.y * 128;

    f32x4 acc[4][4];
#pragma unroll
    for (int mi = 0; mi < 4; ++mi)
#pragma unroll
        for (int ni = 0; ni < 4; ++ni) acc[mi][ni] = (f32x4)0.f;

    for (int k0 = 0; k0 < IN_C; k0 += 32) {
        // ---- stage B: W_ih rows via global_load_lds (16B/lane) ----
#pragma unroll
        for (int e = 0; e < 2; ++e) {
            const int chunk = wv * 2 + e;
            const int nl    = chunk * 16 + (lane >> 2);
            const int q     = (nl >> 4) & 3;
            const int cc    = (nl & 15) + ((nl >> 6) << 4);
            const int grow  = q * H_C + cb * 32 + cc;
            const void* g = (const char*)(wih + grow * IN_C + k0) + (lane & 3) * 16;
            gload_lds16(g, (char*)Bs + chunk * 1024);
        }
        // ---- stage A: x fp32 -> bf16 inline (thread = 16 k of one row) ----
        {
            const int row  = t >> 1;
            const int kh   = (t & 1) * 16;
            const int node = min(m0 + row, N_NODES - 1);
            const float4* xs = (const float4*)(x + (size_t)node * IN_C + k0 + kh);
            const float4 v0 = xs[0], v1 = xs[1], v2 = xs[2], v3 = xs[3];
            bf16x8 o0, o1;
            o0[0] = (__bf16)v0.x; o0[1] = (__bf16)v0.y; o0[2] = (__bf16)v0.z; o0[3] = (__bf16)v0.w;
            o0[4] = (__bf16)v1.x; o0[5] = (__bf16)v1.y; o0[6] = (__bf16)v1.z; o0[7] = (__bf16)v1.w;
            o1[0] = (__bf16)v2.x; o1[1] = (__bf16)v2.y; o1[2] = (__bf16)v2.z; o1[3] = (__bf16)v2.w;
            o1[4] = (__bf16)v3.x; o1[5] = (__bf16)v3.y; o1[6] = (__bf16)v3.z; o1[7] = (__bf16)v3.w;
            bf16x8* dst = (bf16x8*)(As + row * 32 + kh);
            dst[0] = o0;
            dst[1] = o1;
        }
        __syncthreads();
        bf16x8 af[4], bfr[4];
#pragma unroll
        for (int mi = 0; mi < 4; ++mi)
            af[mi] = *(const bf16x8*)(As + (wm * 64 + mi * 16 + l15) * 32 + quad * 8);
#pragma unroll
        for (int ni = 0; ni < 4; ++ni)
            bfr[ni] = *(const bf16x8*)(Bs + (wn * 64 + ni * 16 + l15) * 32 + quad * 8);
#pragma unroll
        for (int mi = 0; mi < 4; ++mi)
#pragma unroll
            for (int ni = 0; ni < 4; ++ni)
                acc[mi][ni] = __builtin_amdgcn_mfma_f32_16x16x32_bf16(
                    af[mi], bfr[ni], acc[mi][ni], 0, 0, 0);
        __syncthreads();
    }

    const int CH = cb * 32 + wn * 16 + l15;
    float bs[4];
#pragma unroll
    for (int q = 0; q < 4; ++q) bs[q] = b_ih[q * H_C + CH] + b_hh[q * H_C + CH];

#pragma unroll
    for (int mi = 0; mi < 4; ++mi) {
#pragma unroll
        for (int r = 0; r < 4; ++r) {
            const int m = m0 + wm * 64 + mi * 16 + quad * 4 + r;
            if (m >= N_NODES) continue;
            if (m >= N_LEAF0) {
                // leaf: mean_h = mean_c = 0
                const float gi = sigm(acc[mi][0][r] + bs[0]);
                const float gf = sigm(acc[mi][1][r] + bs[1]);  (void)gf;
                const float gg = tanh_fast(acc[mi][2][r] + bs[2]);
                const float go = sigm(acc[mi][3][r] + bs[3]);
                const float cn = gi * gg;
                const float hn = go * tanh_fast(cn);
                c[(size_t)m * H_C + CH] = cn;
                hb[(size_t)m * H_C + CH] = (__bf16)hn;
            } else {
#pragma unroll
                for (int q = 0; q < 4; ++q)
                    gx[(size_t)m * 1024 + q * H_C + CH] = (__bf16)acc[mi][q][r];
            }
        }
    }
}

// ---- per-level kernel: gates = gates_x + mean_h @ W_hh^T (K=256), LSTM cell ----
__global__ __launch_bounds__(256)
void level_hw(const __bf16* __restrict__ whh,
              const float* __restrict__ b_ih,
              const float* __restrict__ b_hh,
              const __bf16* __restrict__ gx,
              __bf16* __restrict__ hb,
              float* __restrict__ c,
              int lo, int n)
{
    __shared__ __bf16 As[128 * 32];
    __shared__ __bf16 Bs[128 * 32];

    const int t    = threadIdx.x;
    const int lane = t & 63;
    const int wv   = t >> 6;
    const int wm   = wv >> 1;
    const int wn   = wv & 1;
    const int quad = lane >> 4;
    const int l15  = lane & 15;
    const int cb   = blockIdx.x;
    const int m0   = blockIdx.y * 128;

    f32x4 acc[4][4];
#pragma unroll
    for (int mi = 0; mi < 4; ++mi)
#pragma unroll
        for (int ni = 0; ni < 4; ++ni) acc[mi][ni] = (f32x4)0.f;

    for (int k0 = 0; k0 < H_C; k0 += 32) {
        // ---- stage B: W_hh rows via global_load_lds ----
#pragma unroll
        for (int e = 0; e < 2; ++e) {
            const int chunk = wv * 2 + e;
            const int nl    = chunk * 16 + (lane >> 2);
            const int q     = (nl >> 4) & 3;
            const int cc    = (nl & 15) + ((nl >> 6) << 4);
            const int grow  = q * H_C + cb * 32 + cc;
            const void* g = (const char*)(whh + grow * H_C + k0) + (lane & 3) * 16;
            gload_lds16(g, (char*)Bs + chunk * 1024);
        }
        // ---- stage A: mean of children h (bf16), VGPR-staged ----
        {
            const int row  = t >> 1;
            const int kh   = (t & 1) * 16;
            const int node = lo + m0 + row;
            const int k2   = k0 + kh;
            const bf16x8* hl = (const bf16x8*)(hb + (size_t)(2 * node + 1) * H_C + k2);
            const bf16x8* hr = (const bf16x8*)(hb + (size_t)(2 * node + 2) * H_C + k2);
            const bf16x8 a0 = hl[0], a1 = hl[1], b0 = hr[0], b1 = hr[1];
            bf16x8 o0, o1;
#pragma unroll
            for (int j = 0; j < 8; ++j) {
                o0[j] = (__bf16)(0.5f * ((float)a0[j] + (float)b0[j]));
                o1[j] = (__bf16)(0.5f * ((float)a1[j] + (float)b1[j]));
            }
            bf16x8* dst = (bf16x8*)(As + row * 32 + kh);
            dst[0] = o0;
            dst[1] = o1;
        }
        __syncthreads();
        bf16x8 af[4], bfr[4];
#pragma unroll
        for (int mi = 0; mi < 4; ++mi)
            af[mi] = *(const bf16x8*)(As + (wm * 64 + mi * 16 + l15) * 32 + quad * 8);
#pragma unroll
        for (int ni = 0; ni < 4; ++ni)
            bfr[ni] = *(const bf16x8*)(Bs + (wn * 64 + ni * 16 + l15) * 32 + quad * 8);
#pragma unroll
        for (int mi = 0; mi < 4; ++mi)
#pragma unroll
            for (int ni = 0; ni < 4; ++ni)
                acc[mi][ni] = __builtin_amdgcn_mfma_f32_16x16x32_bf16(
                    af[mi], bfr[ni], acc[mi][ni], 0, 0, 0);
        __syncthreads();
    }

    const int CH = cb * 32 + wn * 16 + l15;
    float bs[4];
#pragma unroll
    for (int q = 0; q < 4; ++q) bs[q] = b_ih[q * H_C + CH] + b_hh[q * H_C + CH];

#pragma unroll
    for (int mi = 0; mi < 4; ++mi) {
#pragma unroll
        for (int r = 0; r < 4; ++r) {
            const int m = m0 + wm * 64 + mi * 16 + quad * 4 + r;
            if (m < n) {
                const int node = lo + m;
                const float g0 = acc[mi][0][r] + (float)gx[(size_t)node * 1024 + 0 * H_C + CH] + bs[0];
                const float g1 = acc[mi][1][r] + (float)gx[(size_t)node * 1024 + 1 * H_C + CH] + bs[1];
                const float g2 = acc[mi][2][r] + (float)gx[(size_t)node * 1024 + 2 * H_C + CH] + bs[2];
                const float g3 = acc[mi][3][r] + (float)gx[(size_t)node * 1024 + 3 * H_C + CH] + bs[3];
                const float gi = sigm(g0);
                const float gf = sigm(g1);
                const float gg = tanh_fast(g2);
                const float go = sigm(g3);
                const float mc = 0.5f * (c[(size_t)(2 * node + 1) * H_C + CH] +
                                         c[(size_t)(2 * node + 2) * H_C + CH]);
                const float cn = gf * mc + gi * gg;
                const float hn = go * tanh_fast(cn);
                c[(size_t)node * H_C + CH] = cn;
                hb[(size_t)node * H_C + CH] = (__bf16)hn;
            }
        }
    }
}

// ---- pooled mean + fc ----
__global__ __launch_bounds__(256)
void reduce_rows(const __bf16* __restrict__ hb, float* __restrict__ part)
{
    const int tcol = threadIdx.x;
    const int b = blockIdx.x;
    float s = 0.f;
    for (int r = 0; r < 128; ++r) {
        const int row = b * 128 + r;
        if (row < N_NODES) s += (float)hb[(size_t)row * H_C + tcol];
    }
    part[b * H_C + tcol] = s;
}

__global__ __launch_bounds__(256)
void reduce_final(const float* __restrict__ part,
                  const float* __restrict__ W_fc,
                  const float* __restrict__ b_fc,
                  float* __restrict__ out)
{
    __shared__ float sm[256];
    const int t = threadIdx.x;
    float s = 0.f;
    for (int j = 0; j < 256; ++j) s += part[j * H_C + t];
    s = s * (1.0f / (float)N_NODES) * W_fc[t];
    sm[t] = s;
    __syncthreads();
    for (int st = 128; st > 0; st >>= 1) {
        if (t < st) sm[t] += sm[t + st];
        __syncthreads();
    }
    if (t == 0) out[0] = sm[0] + b_fc[0];
}

extern "C" void kernel_launch(void* const* d_in, const int* in_sizes, int n_in,
                              void* d_out, int out_size, void* d_ws, size_t ws_size,
                              hipStream_t stream)
{
    const float* x    = (const float*)d_in[0];
    // d_in[1] = edge_index — tree is implicit, unused
    const float* W_ih = (const float*)d_in[2];
    const float* W_hh = (const float*)d_in[3];
    const float* b_ih = (const float*)d_in[4];
    const float* b_hh = (const float*)d_in[5];
    const float* W_fc = (const float*)d_in[6];
    const float* b_fc = (const float*)d_in[7];
    float* out = (float*)d_out;

    // workspace layout (16B aligned), total ~85.7 MB
    char* w = (char*)d_ws;
    __bf16* hb   = (__bf16*)w;  w += (size_t)N_NODES * H_C * 2;       // 16.78 MB
    float*  c    = (float*)w;   w += (size_t)N_NODES * H_C * 4;       // 33.55 MB
    __bf16* gx   = (__bf16*)w;  w += (size_t)N_LEAF0 * 1024 * 2;      // 33.55 MB
    __bf16* wihb = (__bf16*)w;  w += (size_t)4 * H_C * IN_C * 2;      // 1.05 MB
    __bf16* whhb = (__bf16*)w;  w += (size_t)4 * H_C * H_C * 2;       // 0.52 MB
    float*  part = (float*)w;                                          // 0.26 MB

    // convert weights to bf16
    {
        const int n8i = (4 * H_C * IN_C) / 8;   // 65536
        conv_bf16_kernel<<<(n8i + 255) / 256, 256, 0, stream>>>(W_ih, wihb, n8i);
        const int n8h = (4 * H_C * H_C) / 8;    // 32768
        conv_bf16_kernel<<<(n8h + 255) / 256, 256, 0, stream>>>(W_hh, whhb, n8h);
    }

    // bulk: x@W_ih^T for all nodes; leaves fully solved, internal -> gates_x
    {
        dim3 grid(8, 256);   // 256 m-tiles x 128 rows = 32768 >= N_NODES
        bulk_xw<<<grid, 256, 0, stream>>>(x, wihb, b_ih, b_hh, hb, c, gx);
    }
    // internal levels 13..0: K=256 only
    for (int d = 13; d >= 0; --d) {
        const int n  = 1 << d;
        const int lo = n - 1;
        dim3 grid(8, (n + 127) / 128);
        level_hw<<<grid, 256, 0, stream>>>(whhb, b_ih, b_hh, gx, hb, c, lo, n);
    }
    reduce_rows<<<256, 256, 0, stream>>>(hb, part);
    reduce_final<<<1, 256, 0, stream>>>(part, W_fc, b_fc, out);
}